// Round 10
// baseline (69.606 us; speedup 1.0000x reference)
//
#include <hip/hip_runtime.h>
#include <hip/hip_fp16.h>

// CapsuleLinear, B=32, I=512, L=64, O=128, J=64, 3 routing iterations.
// Algebraic fusion (no priors):  out = W_o @ xc,  wn = (G_o @ xc)/||out||,
// G_o = W_o^T W_o (precomputed fp16-packed, lane-major, 1 MB in d_ws).
// MFMA on v_mfma_f32_16x16x32_f16:
//  phase A: logits[i][o] = sum_l x[i][l] wn[o][l]   (b128 LDS, at bank floor)
//  phase B: xc[o][l]     = sum_i coef[o][i] x[i][l] (A: b128; B: x^T fragments
//           in 8 named half8 regs, gathered once via paired-dword broadcast)
// r9 post-mortem: __launch_bounds__(NT,2) let the compiler tier to the
// 256-VGPR/2-waves-per-EU level -> 1 block/CU, cancelling the gather-hoist
// gains. This round: (NT,4) — r2-proven to produce a clean 128-VGPR
// allocation with named/unrolled registers -> 2 blocks/CU AND no spills AND
// one-time gather. Persistent regs = 64 (bf 32 + gq 32) + ~45 temps < 128.

#define CB 32
#define CI 512
#define CL 64
#define CO 128
#define OPB 8
#define NT 512

typedef _Float16 half8 __attribute__((ext_vector_type(8)));
typedef float f32x4 __attribute__((ext_vector_type(4)));

static __device__ __forceinline__ _Float16 half_sel(uint v, int sh) {
  union { unsigned short s; _Float16 h; } c;
  c.s = (unsigned short)(v >> sh);
  return c.h;
}

// Gq layout (as __half2 array): idx = ((o*8 + k)*64 + lane)*4 + q
// holds pair p = 4k+q for column `lane`: (G[o][8k+2q][lane], G[o][8k+2q+1][lane])
// -> per (o,k): 64 lanes x 16 B contiguous = one coalesced uint4 per lane.
__global__ __launch_bounds__(256) void caps_gram(const float* __restrict__ wg,
                                                 __half2* __restrict__ Gq) {
  const int o = blockIdx.x;
  const int t = threadIdx.x;
  __shared__ float wl[64 * 65];  // W[o] padded
  __shared__ float gl[64 * 65];  // G[o] padded
#pragma unroll
  for (int k = 0; k < 16; ++k) {
    int f = t + 256 * k;
    int j = f >> 6, l = f & 63;
    wl[j * 65 + l] = wg[(o << 12) + f];
  }
  __syncthreads();
  const int l1 = t >> 2;
  const int l2b = (t & 3) << 4;
  float acc[16];
#pragma unroll
  for (int m = 0; m < 16; ++m) acc[m] = 0.f;
#pragma unroll 4
  for (int j = 0; j < 64; ++j) {
    float wa = wl[j * 65 + l1];
#pragma unroll
    for (int m = 0; m < 16; ++m) acc[m] += wa * wl[j * 65 + l2b + m];
  }
#pragma unroll
  for (int m = 0; m < 16; ++m) gl[l1 * 65 + l2b + m] = acc[m];
  __syncthreads();
#pragma unroll
  for (int j = 0; j < 8; ++j) {
    int e = t + 256 * j;             // 0..2047
    int k = e >> 8;                  // 0..7
    int l = (e >> 2) & 63;
    int q = e & 3;
    int l2 = 8 * k + 2 * q;
    Gq[(o << 11) + e] = __floats2half2_rn(gl[l2 * 65 + l], gl[(l2 + 1) * 65 + l]);
  }
}

__global__ __launch_bounds__(NT, 4) void caps_main(const float* __restrict__ xg,
                                                   const float* __restrict__ wg,
                                                   const __half2* __restrict__ Gq,
                                                   float* __restrict__ outg) {
  const int b = blockIdx.y;
  const int obase = blockIdx.x * OPB;
  const int t = threadIdx.x;
  const int w = t >> 6;          // wave id
  const int lane = t & 63;
  const int g = lane >> 4;       // 16-lane group
  const int o15 = lane & 15;     // MFMA row/col index
  const int oc = o15 & 7;

  // xs: 32 i-subtiles x 4 l-subtiles, each 16x16 halves row-major = 512 B.
  __shared__ __align__(16) _Float16 xs[CI * CL];        // 65536 B
  __shared__ __align__(16) _Float16 coefT[OPB * CI];    // 8192 B (unit-XOR swz)
  __shared__ __align__(16) _Float16 wn16[OPB * CL];     // 1024 B (unit-XOR swz)
  __shared__ __align__(16) float xc_s[OPB * CL];        // 2048 B
  __shared__ __align__(16) float xcpart[2 * OPB * CL];  // 4096 B (dedicated)
  __shared__ float se_part[OPB * OPB];                  // 256 B
  char* const xs_b = reinterpret_cast<char*>(xs);
  char* const cf_b = reinterpret_cast<char*>(coefT);
  char* const wn_b = reinterpret_cast<char*>(wn16);
  // total 81152 B -> 2 blocks/CU (<= 81920)

  const int kh = w >> 2, nt = w & 3;  // phase-B: K-half, l-subtile

  // ---- G column in 8 named uint4 (fp16 pairs), coalesced one-time load ----
  uint4 gq0, gq1, gq2, gq3, gq4, gq5, gq6, gq7;
  {
    const uint4* Gp = reinterpret_cast<const uint4*>(Gq) +
                      (((obase + w) << 3) << 6) + lane;
    gq0 = Gp[0 * 64]; gq1 = Gp[1 * 64]; gq2 = Gp[2 * 64]; gq3 = Gp[3 * 64];
    gq4 = Gp[4 * 64]; gq5 = Gp[5 * 64]; gq6 = Gp[6 * 64]; gq7 = Gp[7 * 64];
  }

  // ---- stage x[b] -> fp16 subtiled LDS; coalesced float4 global reads ----
  {
    const float4* xg4 = reinterpret_cast<const float4*>(xg + b * (CI * CL));
#pragma unroll
    for (int k = 0; k < 8; ++k) {
      int f = t + NT * k;        // 8-half unit id: row i, l-unit lu
      int i = f >> 3, lu = f & 7;
      float4 a = xg4[2 * f];
      float4 c = xg4[2 * f + 1];
      union { _Float16 h[8]; uint4 u; } cv;
      cv.h[0] = (_Float16)a.x; cv.h[1] = (_Float16)a.y;
      cv.h[2] = (_Float16)a.z; cv.h[3] = (_Float16)a.w;
      cv.h[4] = (_Float16)c.x; cv.h[5] = (_Float16)c.y;
      cv.h[6] = (_Float16)c.z; cv.h[7] = (_Float16)c.w;
      int off = ((i >> 4) * 4 + (lu >> 1)) * 512 + (i & 15) * 32 + (lu & 1) * 16;
      *reinterpret_cast<uint4*>(xs_b + off) = cv.u;
    }
  }
  __syncthreads();

  // ---- x^T B-fragments: gathered ONCE into 8 named half8 regs ----
  // bfK[j] = x[kh*256 + K*32 + 8g + j][nt*16 + o15].
  // Paired-dword trick: lanes o15=2m,2m+1 read the same dword (broadcast),
  // each extracts its half -> conflicts drop from 8-way to ~4-way.
  half8 bf0, bf1, bf2, bf3, bf4, bf5, bf6, bf7;
  {
    const uint* xrd32 = reinterpret_cast<const uint*>(
                            xs_b + ((kh * 16 + (g >> 1)) * 4 + nt) * 512 +
                            ((lane & 16) << 4)) +
                        (o15 >> 1);
    const int sh = (o15 & 1) << 4;
#define GATHER(K)                                                         \
  {                                                                       \
    const uint* xk = xrd32 + (K)*1024; /* +K*4096 B */                    \
    uint q0 = xk[0], q1 = xk[8], q2 = xk[16], q3 = xk[24];                \
    uint q4 = xk[32], q5 = xk[40], q6 = xk[48], q7 = xk[56];              \
    bf##K = (half8){half_sel(q0, sh), half_sel(q1, sh), half_sel(q2, sh), \
                    half_sel(q3, sh), half_sel(q4, sh), half_sel(q5, sh), \
                    half_sel(q6, sh), half_sel(q7, sh)};                  \
  }
    GATHER(0) GATHER(1) GATHER(2) GATHER(3)
    GATHER(4) GATHER(5) GATHER(6) GATHER(7)
#undef GATHER
  }

  for (int pass = 0; pass < 4; ++pass) {
    if (pass > 0) {
      // ---- phase A: logits via MFMA; exp; coef+se ----
      half8 bw0 = *reinterpret_cast<const half8*>(wn_b + oc * 128 + ((g ^ oc) << 4));
      half8 bw1 = *reinterpret_cast<const half8*>(wn_b + oc * 128 + (((4 + g) ^ oc) << 4));
      float sacc = 0.f;
#pragma unroll
      for (int ti = 0; ti < 4; ++ti) {
        const int itb = (16 * w + 4 * ti) * 512;  // i-subtile (4w+ti) byte base
        half8 a0 = *reinterpret_cast<const half8*>(
            xs_b + itb + ((g >> 1) * 512) + o15 * 32 + ((g & 1) << 4));
        half8 a1 = *reinterpret_cast<const half8*>(
            xs_b + itb + ((2 + (g >> 1)) * 512) + o15 * 32 + ((g & 1) << 4));
        f32x4 d = {0.f, 0.f, 0.f, 0.f};
        d = __builtin_amdgcn_mfma_f32_16x16x32_f16(a0, bw0, d, 0, 0, 0);
        d = __builtin_amdgcn_mfma_f32_16x16x32_f16(a1, bw1, d, 0, 0, 0);
        // |logits| <= ||x_i||*sigma_max(W_o) ~ 2.5: no max-subtraction needed
        float e0 = __expf(d[0]), e1 = __expf(d[1]);
        float e2 = __expf(d[2]), e3 = __expf(d[3]);
        sacc += (e0 + e1) + (e2 + e3);
        if (o15 < 8) {  // valid capsule columns only
          int p = 8 * w + 2 * ti + (g >> 1);          // 8-half unit index (i>>3)
          int base = o15 * 1024 + ((p ^ o15) << 4) + ((g & 1) << 3);
          union { _Float16 h[2]; uint u; } p0, p1;
          p0.h[0] = (_Float16)e0; p0.h[1] = (_Float16)e1;
          p1.h[0] = (_Float16)e2; p1.h[1] = (_Float16)e3;
          *reinterpret_cast<uint*>(cf_b + base) = p0.u;
          *reinterpret_cast<uint*>(cf_b + base + 4) = p1.u;
        }
      }
      sacc += __shfl_xor(sacc, 16, 64);
      sacc += __shfl_xor(sacc, 32, 64);
      if (lane < 8) se_part[w * 8 + lane] = sacc;
      __syncthreads();
    }

    // ---- phase B ----
    if (pass == 0) {
      // xbar partials straight from register fragments
      float s = 0.f;
#define SUMF(K)                                                           \
  {                                                                       \
    s += (float)bf##K[0] + (float)bf##K[1] + (float)bf##K[2] +            \
         (float)bf##K[3] + (float)bf##K[4] + (float)bf##K[5] +            \
         (float)bf##K[6] + (float)bf##K[7];                               \
  }
      SUMF(0) SUMF(1) SUMF(2) SUMF(3) SUMF(4) SUMF(5) SUMF(6) SUMF(7)
#undef SUMF
      s += __shfl_xor(s, 16, 64);
      s += __shfl_xor(s, 32, 64);
      if (lane < 16) xcpart[kh * 64 + nt * 16 + o15] = s;  // [2][64] view
    } else {
      // xc partials via MFMA (A=coef b128, B=x^T register fragments)
      f32x4 d = {0.f, 0.f, 0.f, 0.f};
#define MFMAK(K)                                                          \
  {                                                                       \
    int p = kh * 32 + (K)*4 + g;                                          \
    half8 a = *reinterpret_cast<const half8*>(cf_b + oc * 1024 +          \
                                              ((p ^ oc) << 4));           \
    d = __builtin_amdgcn_mfma_f32_16x16x32_f16(a, bf##K, d, 0, 0, 0);     \
  }
      MFMAK(0) MFMAK(1) MFMAK(2) MFMAK(3)
      MFMAK(4) MFMAK(5) MFMAK(6) MFMAK(7)
#undef MFMAK
      if (lane < 32) {  // D rows 0-7 (valid o) live in lanes 0-31
#pragma unroll
        for (int r = 0; r < 4; ++r)
          xcpart[kh * 512 + (g * 4 + r) * 64 + nt * 16 + o15] = d[r];
      }
    }
    __syncthreads();

    // ---- finalize: xc = partials/denom; wn = (G@xc)/||out|| ----
    {
      float xcv;
      if (pass == 0) {
        xcv = (xcpart[lane] + xcpart[64 + lane]) * (1.0f / 512.0f);
      } else {
        float se = 0.f;
#pragma unroll
        for (int g8 = 0; g8 < 8; ++g8) se += se_part[g8 * 8 + w];
        xcv = (xcpart[w * 64 + lane] + xcpart[512 + w * 64 + lane]) / se;
      }
      xc_s[(w << 6) + lane] = xcv;
      if (pass < 3) {
        // u = G @ xc entirely from registers (gq holds fp16 G pairs)
        const float4* xc4 = reinterpret_cast<const float4*>(&xc_s[w << 6]);
        float u0 = 0.f, u1 = 0.f, u2 = 0.f, u3 = 0.f;
#define GDOT(K)                                                           \
  {                                                                       \
    float4 xa = xc4[2 * (K)], xb = xc4[2 * (K) + 1];                      \
    float2 h0 = __half22float2(*reinterpret_cast<const __half2*>(&gq##K.x)); \
    float2 h1 = __half22float2(*reinterpret_cast<const __half2*>(&gq##K.y)); \
    float2 h2 = __half22float2(*reinterpret_cast<const __half2*>(&gq##K.z)); \
    float2 h3 = __half22float2(*reinterpret_cast<const __half2*>(&gq##K.w)); \
    u0 += h0.x * xa.x; u1 += h0.y * xa.y;                                 \
    u2 += h1.x * xa.z; u3 += h1.y * xa.w;                                 \
    u0 += h2.x * xb.x; u1 += h2.y * xb.y;                                 \
    u2 += h3.x * xb.z; u3 += h3.y * xb.w;                                 \
  }
        GDOT(0) GDOT(1) GDOT(2) GDOT(3) GDOT(4) GDOT(5) GDOT(6) GDOT(7)
#undef GDOT
        float uv = (u0 + u1) + (u2 + u3);
        float sq = uv * xcv;
#pragma unroll
        for (int m = 32; m; m >>= 1) sq += __shfl_xor(sq, m, 64);
        float wnv = uv / fmaxf(sqrtf(fmaxf(sq, 0.f)), 1e-12f);
        union { _Float16 hf; unsigned short us; } wc;
        wc.hf = (_Float16)wnv;
        *reinterpret_cast<unsigned short*>(
            wn_b + w * 128 + (((lane >> 3) ^ w) << 4) + ((lane & 7) << 1)) = wc.us;
      }
    }
    __syncthreads();
  }

  // ---- epilogue: out[b, obase+w, j=lane] = sum_l W[o][j][l] * xc[o][l] ----
  {
    const float* Wp = wg + ((((obase + w) << 6) + lane) << 6);
    float a0 = 0.f, a1 = 0.f, a2 = 0.f, a3 = 0.f;
#pragma unroll
    for (int k = 0; k < 16; ++k) {
      float4 wv = *reinterpret_cast<const float4*>(&Wp[k << 2]);
      float4 xv = *reinterpret_cast<const float4*>(&xc_s[(w << 6) + (k << 2)]);
      a0 += wv.x * xv.x; a1 += wv.y * xv.y;
      a2 += wv.z * xv.z; a3 += wv.w * xv.w;
    }
    outg[((b << 7) + obase + w) * 64 + lane] = (a0 + a1) + (a2 + a3);
  }
}

extern "C" void kernel_launch(void* const* d_in, const int* in_sizes, int n_in,
                              void* d_out, int out_size, void* d_ws, size_t ws_size,
                              hipStream_t stream) {
  const float* x = (const float*)d_in[0];     // (32, 512, 64) fp32
  const float* wgt = (const float*)d_in[1];   // (128, 64, 64) fp32
  float* out = (float*)d_out;                 // (32, 128, 64) fp32
  __half2* Gq = (__half2*)d_ws;               // 128*8*64*4 __half2 = 1 MB

  caps_gram<<<dim3(CO), dim3(256), 0, stream>>>(wgt, Gq);
  caps_main<<<dim3(CO / OPB, CB), dim3(NT), 0, stream>>>(x, wgt, Gq, out);
}

// Round 11
// 42.998 us; speedup vs baseline: 1.6188x; 1.6188x over previous
//
#include <hip/hip_runtime.h>
#include <hip/hip_fp16.h>

// CapsuleLinear, B=32, I=512, L=64, O=128, J=64, 3 routing iterations.
// Algebraic fusion (no priors):  out = W_o @ xc,  wn = (G_o @ xc)/||out||,
// G_o = W_o^T W_o (precomputed fp16-packed lane-major Gq, 1 MB in d_ws).
// MFMA on v_mfma_f32_16x16x32_f16:
//  phase A: logits[i][o] = sum_l x[i][l] wn[o][l]   (b128 LDS, bank floor)
//  phase B: xc[o][l]     = sum_i coef[o][i] x[i][l] (A: b128; B: x^T gathered
//           per pass via PAIRED-DWORD broadcast reads, built per-K inside the
//           MFMA loop)
// Design rule learned r5-r10: this compiler pins 512-thread blocks at 64
// VGPRs (81KB-LDS configs) and spills any persistent register state to
// scratch (WRITE_SIZE 57-93 MB). So: NOTHING persists across passes.
//  - x^T re-gathered each pass, paired-dword (4-way conflict, not 8-way)
//  - G (fp16, lane-major) prefetched at phase-B start, consumed in finalize,
//    dead by pass end -- latency hidden under gather+MFMA, no spill window

#define CB 32
#define CI 512
#define CL 64
#define CO 128
#define OPB 8
#define NT 512

typedef _Float16 half8 __attribute__((ext_vector_type(8)));
typedef float f32x4 __attribute__((ext_vector_type(4)));

static __device__ __forceinline__ _Float16 half_sel(uint v, int sh) {
  union { unsigned short s; _Float16 h; } c;
  c.s = (unsigned short)(v >> sh);
  return c.h;
}

// Gq layout (as __half2 array): idx = ((o*8 + k)*64 + lane)*4 + q
// holds pair p = 4k+q for column `lane`: (G[o][8k+2q][lane], G[o][8k+2q+1][lane])
// -> per (o,k): 64 lanes x 16 B contiguous = one coalesced uint4 per lane.
__global__ __launch_bounds__(256) void caps_gram(const float* __restrict__ wg,
                                                 __half2* __restrict__ Gq) {
  const int o = blockIdx.x;
  const int t = threadIdx.x;
  __shared__ float wl[64 * 65];  // W[o] padded
  __shared__ float gl[64 * 65];  // G[o] padded
#pragma unroll
  for (int k = 0; k < 16; ++k) {
    int f = t + 256 * k;
    int j = f >> 6, l = f & 63;
    wl[j * 65 + l] = wg[(o << 12) + f];
  }
  __syncthreads();
  const int l1 = t >> 2;
  const int l2b = (t & 3) << 4;
  float acc[16];
#pragma unroll
  for (int m = 0; m < 16; ++m) acc[m] = 0.f;
#pragma unroll 4
  for (int j = 0; j < 64; ++j) {
    float wa = wl[j * 65 + l1];
#pragma unroll
    for (int m = 0; m < 16; ++m) acc[m] += wa * wl[j * 65 + l2b + m];
  }
#pragma unroll
  for (int m = 0; m < 16; ++m) gl[l1 * 65 + l2b + m] = acc[m];
  __syncthreads();
#pragma unroll
  for (int j = 0; j < 8; ++j) {
    int e = t + 256 * j;             // 0..2047
    int k = e >> 8;                  // 0..7
    int l = (e >> 2) & 63;
    int q = e & 3;
    int l2 = 8 * k + 2 * q;
    Gq[(o << 11) + e] = __floats2half2_rn(gl[l2 * 65 + l], gl[(l2 + 1) * 65 + l]);
  }
}

__global__ __launch_bounds__(NT, 4) void caps_main(const float* __restrict__ xg,
                                                   const float* __restrict__ wg,
                                                   const __half2* __restrict__ Gq,
                                                   float* __restrict__ outg) {
  const int b = blockIdx.y;
  const int obase = blockIdx.x * OPB;
  const int t = threadIdx.x;
  const int w = t >> 6;          // wave id
  const int lane = t & 63;
  const int g = lane >> 4;       // 16-lane group
  const int o15 = lane & 15;     // MFMA row/col index
  const int oc = o15 & 7;

  // xs: 32 i-subtiles x 4 l-subtiles, each 16x16 halves row-major = 512 B.
  __shared__ __align__(16) _Float16 xs[CI * CL];        // 65536 B
  __shared__ __align__(16) _Float16 coefT[OPB * CI];    // 8192 B (unit-XOR swz)
  __shared__ __align__(16) _Float16 wn16[OPB * CL];     // 1024 B (unit-XOR swz)
  __shared__ __align__(16) float xc_s[OPB * CL];        // 2048 B
  __shared__ __align__(16) float xcpart[2 * OPB * CL];  // 4096 B (dedicated)
  __shared__ float se_part[OPB * OPB];                  // 256 B
  char* const xs_b = reinterpret_cast<char*>(xs);
  char* const cf_b = reinterpret_cast<char*>(coefT);
  char* const wn_b = reinterpret_cast<char*>(wn16);
  // total 81152 B -> 2 blocks/CU (<= 81920)

  const int kh = w >> 2, nt = w & 3;  // phase-B: K-half, l-subtile

  // ---- stage x[b] -> fp16 subtiled LDS; coalesced float4 global reads ----
  {
    const float4* xg4 = reinterpret_cast<const float4*>(xg + b * (CI * CL));
#pragma unroll
    for (int k = 0; k < 8; ++k) {
      int f = t + NT * k;        // 8-half unit id: row i, l-unit lu
      int i = f >> 3, lu = f & 7;
      float4 a = xg4[2 * f];
      float4 c = xg4[2 * f + 1];
      union { _Float16 h[8]; uint4 u; } cv;
      cv.h[0] = (_Float16)a.x; cv.h[1] = (_Float16)a.y;
      cv.h[2] = (_Float16)a.z; cv.h[3] = (_Float16)a.w;
      cv.h[4] = (_Float16)c.x; cv.h[5] = (_Float16)c.y;
      cv.h[6] = (_Float16)c.z; cv.h[7] = (_Float16)c.w;
      int off = ((i >> 4) * 4 + (lu >> 1)) * 512 + (i & 15) * 32 + (lu & 1) * 16;
      *reinterpret_cast<uint4*>(xs_b + off) = cv.u;
    }
  }
  __syncthreads();

  // paired-dword gather base: lanes o15=2m,2m+1 read the same dword
  // (LDS broadcast), each extracts its half -> 4-way conflict, not 8-way.
  const uint* xrd32 = reinterpret_cast<const uint*>(
                          xs_b + ((kh * 16 + (g >> 1)) * 4 + nt) * 512 +
                          ((lane & 16) << 4)) +
                      (o15 >> 1);
  const int sh = (o15 & 1) << 4;
  const uint4* Gp = reinterpret_cast<const uint4*>(Gq) +
                    (((obase + w) << 3) << 6) + lane;

  // per-pass transient G registers (prefetched in phase B, dead by pass end)
  uint4 gq0, gq1, gq2, gq3, gq4, gq5, gq6, gq7;
#define PREFETCH_GQ()                                                     \
  {                                                                       \
    gq0 = Gp[0 * 64]; gq1 = Gp[1 * 64]; gq2 = Gp[2 * 64]; gq3 = Gp[3 * 64]; \
    gq4 = Gp[4 * 64]; gq5 = Gp[5 * 64]; gq6 = Gp[6 * 64]; gq7 = Gp[7 * 64]; \
  }

  for (int pass = 0; pass < 4; ++pass) {
    if (pass > 0) {
      // ---- phase A: logits via MFMA; exp; coef+se ----
      half8 bw0 = *reinterpret_cast<const half8*>(wn_b + oc * 128 + ((g ^ oc) << 4));
      half8 bw1 = *reinterpret_cast<const half8*>(wn_b + oc * 128 + (((4 + g) ^ oc) << 4));
      float sacc = 0.f;
#pragma unroll
      for (int ti = 0; ti < 4; ++ti) {
        const int itb = (16 * w + 4 * ti) * 512;  // i-subtile (4w+ti) byte base
        half8 a0 = *reinterpret_cast<const half8*>(
            xs_b + itb + ((g >> 1) * 512) + o15 * 32 + ((g & 1) << 4));
        half8 a1 = *reinterpret_cast<const half8*>(
            xs_b + itb + ((2 + (g >> 1)) * 512) + o15 * 32 + ((g & 1) << 4));
        f32x4 d = {0.f, 0.f, 0.f, 0.f};
        d = __builtin_amdgcn_mfma_f32_16x16x32_f16(a0, bw0, d, 0, 0, 0);
        d = __builtin_amdgcn_mfma_f32_16x16x32_f16(a1, bw1, d, 0, 0, 0);
        // |logits| <= ||x_i||*sigma_max(W_o) ~ 2.5: no max-subtraction needed
        float e0 = __expf(d[0]), e1 = __expf(d[1]);
        float e2 = __expf(d[2]), e3 = __expf(d[3]);
        sacc += (e0 + e1) + (e2 + e3);
        if (o15 < 8) {  // valid capsule columns only
          int p = 8 * w + 2 * ti + (g >> 1);          // 8-half unit index (i>>3)
          int base = o15 * 1024 + ((p ^ o15) << 4) + ((g & 1) << 3);
          union { _Float16 h[2]; uint u; } p0, p1;
          p0.h[0] = (_Float16)e0; p0.h[1] = (_Float16)e1;
          p1.h[0] = (_Float16)e2; p1.h[1] = (_Float16)e3;
          *reinterpret_cast<uint*>(cf_b + base) = p0.u;
          *reinterpret_cast<uint*>(cf_b + base + 4) = p1.u;
        }
      }
      sacc += __shfl_xor(sacc, 16, 64);
      sacc += __shfl_xor(sacc, 32, 64);
      if (lane < 8) se_part[w * 8 + lane] = sacc;
      __syncthreads();
    }

    // ---- phase B ----
    if (pass < 3) PREFETCH_GQ();  // in flight while gather+MFMA run
    if (pass == 0) {
      // xbar partials: paired-dword gather, sum own column
      float s = 0.f;
#define SUMK(K)                                                           \
  {                                                                       \
    const uint* xk = xrd32 + (K)*1024;                                    \
    s += (float)half_sel(xk[0], sh) + (float)half_sel(xk[8], sh) +        \
         (float)half_sel(xk[16], sh) + (float)half_sel(xk[24], sh) +      \
         (float)half_sel(xk[32], sh) + (float)half_sel(xk[40], sh) +      \
         (float)half_sel(xk[48], sh) + (float)half_sel(xk[56], sh);       \
  }
      SUMK(0) SUMK(1) SUMK(2) SUMK(3) SUMK(4) SUMK(5) SUMK(6) SUMK(7)
#undef SUMK
      s += __shfl_xor(s, 16, 64);
      s += __shfl_xor(s, 32, 64);
      if (lane < 16) xcpart[kh * 64 + nt * 16 + o15] = s;  // [2][64] view
    } else {
      // xc partials via MFMA; B-fragment built per-K from paired-dword reads
      f32x4 d = {0.f, 0.f, 0.f, 0.f};
#define MFMAK(K)                                                          \
  {                                                                       \
    const uint* xk = xrd32 + (K)*1024; /* +K*4096 B */                    \
    uint q0 = xk[0], q1 = xk[8], q2 = xk[16], q3 = xk[24];                \
    uint q4 = xk[32], q5 = xk[40], q6 = xk[48], q7 = xk[56];              \
    half8 bfv = (half8){half_sel(q0, sh), half_sel(q1, sh),               \
                        half_sel(q2, sh), half_sel(q3, sh),               \
                        half_sel(q4, sh), half_sel(q5, sh),               \
                        half_sel(q6, sh), half_sel(q7, sh)};              \
    int p = kh * 32 + (K)*4 + g;                                          \
    half8 a = *reinterpret_cast<const half8*>(cf_b + oc * 1024 +          \
                                              ((p ^ oc) << 4));           \
    d = __builtin_amdgcn_mfma_f32_16x16x32_f16(a, bfv, d, 0, 0, 0);       \
  }
      MFMAK(0) MFMAK(1) MFMAK(2) MFMAK(3)
      MFMAK(4) MFMAK(5) MFMAK(6) MFMAK(7)
#undef MFMAK
      if (lane < 32) {  // D rows 0-7 (valid o) live in lanes 0-31
#pragma unroll
        for (int r = 0; r < 4; ++r)
          xcpart[kh * 512 + (g * 4 + r) * 64 + nt * 16 + o15] = d[r];
      }
    }
    __syncthreads();

    // ---- finalize: xc = partials/denom; wn = (G@xc)/||out|| ----
    {
      float xcv;
      if (pass == 0) {
        xcv = (xcpart[lane] + xcpart[64 + lane]) * (1.0f / 512.0f);
      } else {
        float se = 0.f;
#pragma unroll
        for (int g8 = 0; g8 < 8; ++g8) se += se_part[g8 * 8 + w];
        xcv = (xcpart[w * 64 + lane] + xcpart[512 + w * 64 + lane]) / se;
      }
      xc_s[(w << 6) + lane] = xcv;
      if (pass < 3) {
        // u = G @ xc from the prefetched fp16 G pairs
        const float4* xc4 = reinterpret_cast<const float4*>(&xc_s[w << 6]);
        float u0 = 0.f, u1 = 0.f, u2 = 0.f, u3 = 0.f;
#define GDOT(K)                                                           \
  {                                                                       \
    float4 xa = xc4[2 * (K)], xb = xc4[2 * (K) + 1];                      \
    float2 h0 = __half22float2(*reinterpret_cast<const __half2*>(&gq##K.x)); \
    float2 h1 = __half22float2(*reinterpret_cast<const __half2*>(&gq##K.y)); \
    float2 h2 = __half22float2(*reinterpret_cast<const __half2*>(&gq##K.z)); \
    float2 h3 = __half22float2(*reinterpret_cast<const __half2*>(&gq##K.w)); \
    u0 += h0.x * xa.x; u1 += h0.y * xa.y;                                 \
    u2 += h1.x * xa.z; u3 += h1.y * xa.w;                                 \
    u0 += h2.x * xb.x; u1 += h2.y * xb.y;                                 \
    u2 += h3.x * xb.z; u3 += h3.y * xb.w;                                 \
  }
        GDOT(0) GDOT(1) GDOT(2) GDOT(3) GDOT(4) GDOT(5) GDOT(6) GDOT(7)
#undef GDOT
        float uv = (u0 + u1) + (u2 + u3);
        float sq = uv * xcv;
#pragma unroll
        for (int m = 32; m; m >>= 1) sq += __shfl_xor(sq, m, 64);
        float wnv = uv / fmaxf(sqrtf(fmaxf(sq, 0.f)), 1e-12f);
        union { _Float16 hf; unsigned short us; } wc;
        wc.hf = (_Float16)wnv;
        *reinterpret_cast<unsigned short*>(
            wn_b + w * 128 + (((lane >> 3) ^ w) << 4) + ((lane & 7) << 1)) = wc.us;
      }
    }
    __syncthreads();
  }

  // ---- epilogue: out[b, obase+w, j=lane] = sum_l W[o][j][l] * xc[o][l] ----
  {
    const float* Wp = wg + ((((obase + w) << 6) + lane) << 6);
    float a0 = 0.f, a1 = 0.f, a2 = 0.f, a3 = 0.f;
#pragma unroll
    for (int k = 0; k < 16; ++k) {
      float4 wv = *reinterpret_cast<const float4*>(&Wp[k << 2]);
      float4 xv = *reinterpret_cast<const float4*>(&xc_s[(w << 6) + (k << 2)]);
      a0 += wv.x * xv.x; a1 += wv.y * xv.y;
      a2 += wv.z * xv.z; a3 += wv.w * xv.w;
    }
    outg[((b << 7) + obase + w) * 64 + lane] = (a0 + a1) + (a2 + a3);
  }
}

extern "C" void kernel_launch(void* const* d_in, const int* in_sizes, int n_in,
                              void* d_out, int out_size, void* d_ws, size_t ws_size,
                              hipStream_t stream) {
  const float* x = (const float*)d_in[0];     // (32, 512, 64) fp32
  const float* wgt = (const float*)d_in[1];   // (128, 64, 64) fp32
  float* out = (float*)d_out;                 // (32, 128, 64) fp32
  __half2* Gq = (__half2*)d_ws;               // 128*8*64*4 __half2 = 1 MB

  caps_gram<<<dim3(CO), dim3(256), 0, stream>>>(wgt, Gq);
  caps_main<<<dim3(CO / OPB, CB), dim3(NT), 0, stream>>>(x, wgt, Gq, out);
}

// Round 12
// 37.754 us; speedup vs baseline: 1.8437x; 1.1389x over previous
//
#include <hip/hip_runtime.h>
#include <hip/hip_fp16.h>

// CapsuleLinear, B=32, I=512, L=64, O=128, J=64, 3 routing iterations.
// Algebraic fusion (no priors): out = W_o @ xc, wn = (G_o @ xc)/||out||,
// G_o = W_o^T W_o (fp16-packed lane-major Gq, 1 MB in d_ws).
// r12 structural change: x held in LDS in BOTH layouts.
//   xs  [32 i-sub][4 l-sub][16][16]  -> phase A A-frags (b128, conflict-free)
//   xT  [64 l][512 i] XOR-swizzled   -> phase B B-frags (b128, conflict-free)
// xT is built ONCE by the paired-dword gather (r4-r11 paid it every pass; it
// was the dominant LDS-pipe cost). 16 capsules/block (full 16-row MFMA in
// phase B -- r3-r11 wasted half), NT=1024, grid=256 = exactly 1 block/CU,
// LDS 154.6 KB. xcpart overlays coefT (barrier-separated).

#define CB 32
#define CI 512
#define CL 64
#define CO 128
#define OPB 16
#define NT 1024

typedef _Float16 half8 __attribute__((ext_vector_type(8)));
typedef float f32x4 __attribute__((ext_vector_type(4)));

static __device__ __forceinline__ _Float16 half_sel(uint v, int sh) {
  union { unsigned short s; _Float16 h; } c;
  c.s = (unsigned short)(v >> sh);
  return c.h;
}

// Gq layout (as __half2 array): idx = ((o*8 + k)*64 + lane)*4 + qq
// holds pair p = 4k+qq for col lane: (G[o][8k+2qq][lane], G[o][8k+2qq+1][lane])
__global__ __launch_bounds__(256) void caps_gram(const float* __restrict__ wg,
                                                 __half2* __restrict__ Gq) {
  const int o = blockIdx.x;
  const int t = threadIdx.x;
  __shared__ float wl[64 * 65];
  __shared__ float gl[64 * 65];
#pragma unroll
  for (int k = 0; k < 16; ++k) {
    int f = t + 256 * k;
    int j = f >> 6, l = f & 63;
    wl[j * 65 + l] = wg[(o << 12) + f];
  }
  __syncthreads();
  const int l1 = t >> 2;
  const int l2b = (t & 3) << 4;
  float acc[16];
#pragma unroll
  for (int m = 0; m < 16; ++m) acc[m] = 0.f;
#pragma unroll 4
  for (int j = 0; j < 64; ++j) {
    float wa = wl[j * 65 + l1];
#pragma unroll
    for (int m = 0; m < 16; ++m) acc[m] += wa * wl[j * 65 + l2b + m];
  }
#pragma unroll
  for (int m = 0; m < 16; ++m) gl[l1 * 65 + l2b + m] = acc[m];
  __syncthreads();
#pragma unroll
  for (int j = 0; j < 8; ++j) {
    int e = t + 256 * j;
    int k = e >> 8;
    int l = (e >> 2) & 63;
    int qq = e & 3;
    int l2 = 8 * k + 2 * qq;
    Gq[(o << 11) + e] = __floats2half2_rn(gl[l2 * 65 + l], gl[(l2 + 1) * 65 + l]);
  }
}

__global__ __launch_bounds__(NT, 4) void caps_main(const float* __restrict__ xg,
                                                   const float* __restrict__ wg,
                                                   const __half2* __restrict__ Gq,
                                                   float* __restrict__ outg) {
  const int b = blockIdx.y;
  const int obase = blockIdx.x * OPB;
  const int t = threadIdx.x;
  const int w = t >> 6;          // wave 0..15, owns capsule o = obase + w
  const int lane = t & 63;
  const int g = lane >> 4;
  const int o15 = lane & 15;

  __shared__ __align__(16) _Float16 xs[CI * CL];       // 65536 B
  __shared__ __align__(16) _Float16 xT[CL * CI];       // 65536 B (swizzled)
  __shared__ __align__(16) _Float16 coefT[OPB * CI];   // 16384 B (+xcpart ovl)
  __shared__ __align__(16) _Float16 wn16[OPB * CL];    // 2048 B (swizzled)
  __shared__ __align__(16) float xc_s[OPB * CL];       // 4096 B
  __shared__ float se_part[OPB * OPB];                 // 1024 B
  float* const xcpart = reinterpret_cast<float*>(coefT);  // [4][16][64] view
  char* const xs_b = reinterpret_cast<char*>(xs);
  char* const xT_b = reinterpret_cast<char*>(xT);
  char* const cf_b = reinterpret_cast<char*>(coefT);
  char* const wn_b = reinterpret_cast<char*>(wn16);
  // total 154624 B -> 1 block/CU, grid 256 = one full-chip round

  const int qh = w >> 2, nt = w & 3;  // phase-B: i-quarter, l-subtile
  const int lcol = nt * 16 + o15;     // this lane's xT row (l index)

  // ---- stage x[b] -> fp16 subtiled LDS; coalesced float4 global reads ----
  {
    const float4* xg4 = reinterpret_cast<const float4*>(xg + b * (CI * CL));
#pragma unroll
    for (int k = 0; k < 4; ++k) {
      int f = t + NT * k;        // 8-half unit id: row i, l-unit lu
      int i = f >> 3, lu = f & 7;
      float4 a = xg4[2 * f];
      float4 c = xg4[2 * f + 1];
      union { _Float16 h[8]; uint4 u; } cv;
      cv.h[0] = (_Float16)a.x; cv.h[1] = (_Float16)a.y;
      cv.h[2] = (_Float16)a.z; cv.h[3] = (_Float16)a.w;
      cv.h[4] = (_Float16)c.x; cv.h[5] = (_Float16)c.y;
      cv.h[6] = (_Float16)c.z; cv.h[7] = (_Float16)c.w;
      int off = ((i >> 4) * 4 + (lu >> 1)) * 512 + (i & 15) * 32 + (lu & 1) * 16;
      *reinterpret_cast<uint4*>(xs_b + off) = cv.u;
    }
  }
  __syncthreads();

  // per-pass transient G registers (fp16 pairs)
  uint4 gq0, gq1, gq2, gq3, gq4, gq5, gq6, gq7;
  const uint4* Gp = reinterpret_cast<const uint4*>(Gq) +
                    (((obase + w) << 3) << 6) + lane;
#define PREFETCH_GQ()                                                       \
  {                                                                         \
    gq0 = Gp[0 * 64]; gq1 = Gp[1 * 64]; gq2 = Gp[2 * 64]; gq3 = Gp[3 * 64]; \
    gq4 = Gp[4 * 64]; gq5 = Gp[5 * 64]; gq6 = Gp[6 * 64]; gq7 = Gp[7 * 64]; \
  }

  // ---- build xT ONCE: paired-dword gather from xs -> swizzled xT rows ----
  // lane (g,o15) of wave (qh,nt): col l = lcol, i-units P = qh*16 + K*4 + g.
  // Also accumulates xbar partials (pass 0's phase B).
  {
    const uint* xrd32 = reinterpret_cast<const uint*>(
                            xs_b + nt * 512 + ((o15 & 8) << 1)) +
                        ((o15 & 7) >> 1);
    const int sh = (o15 & 1) << 4;
    float xbs = 0.f;
#define GATHW(K)                                                            \
  {                                                                         \
    int P = qh * 16 + (K)*4 + g;                                            \
    const uint* xk = xrd32 + (P >> 1) * 512 + (P & 1) * 64;                 \
    uint d0 = xk[0], d1 = xk[8], d2 = xk[16], d3 = xk[24];                  \
    uint d4 = xk[32], d5 = xk[40], d6 = xk[48], d7 = xk[56];                \
    union { _Float16 h[8]; uint4 u; } fv;                                   \
    fv.h[0] = half_sel(d0, sh); fv.h[1] = half_sel(d1, sh);                 \
    fv.h[2] = half_sel(d2, sh); fv.h[3] = half_sel(d3, sh);                 \
    fv.h[4] = half_sel(d4, sh); fv.h[5] = half_sel(d5, sh);                 \
    fv.h[6] = half_sel(d6, sh); fv.h[7] = half_sel(d7, sh);                 \
    xbs += (float)fv.h[0] + (float)fv.h[1] + (float)fv.h[2] +               \
           (float)fv.h[3] + (float)fv.h[4] + (float)fv.h[5] +               \
           (float)fv.h[6] + (float)fv.h[7];                                 \
    *reinterpret_cast<uint4*>(xT_b + lcol * 1024 +                          \
                              ((P ^ (lcol & 7)) << 4)) = fv.u;              \
  }
    GATHW(0) GATHW(1) GATHW(2) GATHW(3)
#undef GATHW
    xbs += __shfl_xor(xbs, 16, 64);
    xbs += __shfl_xor(xbs, 32, 64);
    if (lane < 16) xcpart[qh * 1024 + nt * 16 + lane] = xbs;  // [4][64] view
    PREFETCH_GQ();
  }
  __syncthreads();

  for (int pass = 0; pass < 4; ++pass) {
    if (pass > 0) {
      // ---- phase A: logits for 16 o's via MFMA; exp; coefT + se_part ----
      half8 bw0 = *reinterpret_cast<const half8*>(
          wn_b + o15 * 128 + ((g ^ (o15 & 7)) << 4));
      half8 bw1 = *reinterpret_cast<const half8*>(
          wn_b + o15 * 128 + (((4 + g) ^ (o15 & 7)) << 4));
      float sacc = 0.f;
#pragma unroll
      for (int ti = 0; ti < 2; ++ti) {
        const int st = 2 * w + ti;            // i-subtile, rows st*16..+15
        const int itb = st * 2048;
        half8 a0 = *reinterpret_cast<const half8*>(
            xs_b + itb + ((g >> 1) * 512) + o15 * 32 + ((g & 1) << 4));
        half8 a1 = *reinterpret_cast<const half8*>(
            xs_b + itb + ((2 + (g >> 1)) * 512) + o15 * 32 + ((g & 1) << 4));
        f32x4 d = {0.f, 0.f, 0.f, 0.f};
        d = __builtin_amdgcn_mfma_f32_16x16x32_f16(a0, bw0, d, 0, 0, 0);
        d = __builtin_amdgcn_mfma_f32_16x16x32_f16(a1, bw1, d, 0, 0, 0);
        // |logits| <= ||x_i||*sigma_max(W) ~ 2.5: softmax w/o max-sub is safe
        float e0 = __expf(d[0]), e1 = __expf(d[1]);
        float e2 = __expf(d[2]), e3 = __expf(d[3]);
        sacc += (e0 + e1) + (e2 + e3);
        // D: col=o15 -> o, row=g*4+r -> i = st*16+g*4+r; 4 contig halves
        int p = st * 2 + (g >> 1);
        union { _Float16 h[4]; uint2 u; } pk;
        pk.h[0] = (_Float16)e0; pk.h[1] = (_Float16)e1;
        pk.h[2] = (_Float16)e2; pk.h[3] = (_Float16)e3;
        *reinterpret_cast<uint2*>(cf_b + o15 * 1024 + ((p ^ o15) << 4) +
                                  ((g & 1) << 3)) = pk.u;
      }
      sacc += __shfl_xor(sacc, 16, 64);
      sacc += __shfl_xor(sacc, 32, 64);
      if (lane < 16) se_part[w * 16 + lane] = sacc;  // [i-wave][o]
      __syncthreads();

      // ---- phase B: xc partials, full 16-row MFMA, all b128 ----
      f32x4 d = {0.f, 0.f, 0.f, 0.f};
#define MFMAK(K)                                                            \
  {                                                                         \
    int p = qh * 16 + (K)*4 + g;                                            \
    half8 a = *reinterpret_cast<const half8*>(cf_b + o15 * 1024 +           \
                                              ((p ^ o15) << 4));            \
    half8 bv = *reinterpret_cast<const half8*>(xT_b + lcol * 1024 +         \
                                               ((p ^ (lcol & 7)) << 4));    \
    d = __builtin_amdgcn_mfma_f32_16x16x32_f16(a, bv, d, 0, 0, 0);          \
  }
      MFMAK(0) MFMAK(1) MFMAK(2) MFMAK(3)
#undef MFMAK
      if (pass < 3) PREFETCH_GQ();
      __syncthreads();  // all coefT reads done before overlay write
#pragma unroll
      for (int r = 0; r < 4; ++r)
        xcpart[qh * 1024 + (g * 4 + r) * 64 + lcol] = d[r];  // [q][o][l]
    }
    __syncthreads();

    // ---- finalize: xc = partials/denom; wn = (G@xc)/||out|| ----
    {
      float xcv;
      if (pass == 0) {
        xcv = (xcpart[lane] + xcpart[1024 + lane] + xcpart[2048 + lane] +
               xcpart[3072 + lane]) * (1.0f / 512.0f);
      } else {
        float se = 0.f;
#pragma unroll
        for (int j = 0; j < 16; ++j) se += se_part[j * 16 + w];
        float sxc = xcpart[w * 64 + lane] + xcpart[1024 + w * 64 + lane] +
                    xcpart[2048 + w * 64 + lane] + xcpart[3072 + w * 64 + lane];
        xcv = sxc / se;
      }
      xc_s[(w << 6) + lane] = xcv;
      if (pass < 3) {
        const float4* xc4 = reinterpret_cast<const float4*>(&xc_s[w << 6]);
        float u0 = 0.f, u1 = 0.f, u2 = 0.f, u3 = 0.f;
#define GDOT(K)                                                             \
  {                                                                         \
    float4 xa = xc4[2 * (K)], xb = xc4[2 * (K) + 1];                        \
    float2 h0 = __half22float2(*reinterpret_cast<const __half2*>(&gq##K.x)); \
    float2 h1 = __half22float2(*reinterpret_cast<const __half2*>(&gq##K.y)); \
    float2 h2 = __half22float2(*reinterpret_cast<const __half2*>(&gq##K.z)); \
    float2 h3 = __half22float2(*reinterpret_cast<const __half2*>(&gq##K.w)); \
    u0 += h0.x * xa.x; u1 += h0.y * xa.y;                                   \
    u2 += h1.x * xa.z; u3 += h1.y * xa.w;                                   \
    u0 += h2.x * xb.x; u1 += h2.y * xb.y;                                   \
    u2 += h3.x * xb.z; u3 += h3.y * xb.w;                                   \
  }
        GDOT(0) GDOT(1) GDOT(2) GDOT(3) GDOT(4) GDOT(5) GDOT(6) GDOT(7)
#undef GDOT
        float uv = (u0 + u1) + (u2 + u3);
        float sq = uv * xcv;
#pragma unroll
        for (int m = 32; m; m >>= 1) sq += __shfl_xor(sq, m, 64);
        float wnv = uv / fmaxf(sqrtf(fmaxf(sq, 0.f)), 1e-12f);
        union { _Float16 hf; unsigned short us; } wc;
        wc.hf = (_Float16)wnv;
        *reinterpret_cast<unsigned short*>(
            wn_b + w * 128 + (((lane >> 3) ^ (w & 7)) << 4) +
            ((lane & 7) << 1)) = wc.us;
      }
    }
    __syncthreads();
  }

  // ---- epilogue: out[b, obase+w, j=lane] = sum_l W[o][j][l] * xc[o][l] ----
  {
    const float* Wp = wg + ((((obase + w) << 6) + lane) << 6);
    float a0 = 0.f, a1 = 0.f, a2 = 0.f, a3 = 0.f;
#pragma unroll
    for (int k = 0; k < 16; ++k) {
      float4 wv = *reinterpret_cast<const float4*>(&Wp[k << 2]);
      float4 xv = *reinterpret_cast<const float4*>(&xc_s[(w << 6) + (k << 2)]);
      a0 += wv.x * xv.x; a1 += wv.y * xv.y;
      a2 += wv.z * xv.z; a3 += wv.w * xv.w;
    }
    outg[((b << 7) + obase + w) * 64 + lane] = (a0 + a1) + (a2 + a3);
  }
#undef PREFETCH_GQ
}

extern "C" void kernel_launch(void* const* d_in, const int* in_sizes, int n_in,
                              void* d_out, int out_size, void* d_ws, size_t ws_size,
                              hipStream_t stream) {
  const float* x = (const float*)d_in[0];     // (32, 512, 64) fp32
  const float* wgt = (const float*)d_in[1];   // (128, 64, 64) fp32
  float* out = (float*)d_out;                 // (32, 128, 64) fp32
  __half2* Gq = (__half2*)d_ws;               // 128*8*64*4 __half2 = 1 MB

  caps_gram<<<dim3(CO), dim3(256), 0, stream>>>(wgt, Gq);
  caps_main<<<dim3(CO / OPB, CB), dim3(NT), 0, stream>>>(x, wgt, Gq, out);
}

// Round 13
// 35.176 us; speedup vs baseline: 1.9788x; 1.0733x over previous
//
#include <hip/hip_runtime.h>
#include <hip/hip_fp16.h>

// CapsuleLinear, B=32, I=512, L=64, O=128, J=64, 3 routing iterations.
// Algebraic fusion (no priors): out = W_o @ xc, wn = (G_o @ xc)/||W_o xc||,
// G_o = W_o^T W_o (fp16 lane-major Gq, 1 MB in d_ws).
// Key r13 changes vs r12:
//  - SCALE INVARIANCE: wn is invariant to xc scale, so softmax denominator se
//    and the /512 mean are applied ONLY in the final pass. Passes 0-2 carry
//    unnormalized xc (exact algebra, fp32 range fine).
//  - G-dot split into two 16-reg coalesced batches (issue batch1 at phase-B
//    start, batch2 in finalize): peak extra live regs 16, total ~45 < 64 ->
//    nothing for the 64-VGPR-happy allocator to spill (r6/r7/r10 pathology).
//  - caps_gram split over 256 blocks (full chip), direct fp16 store.
// LDS: xs 64K (phase-A A-frags) + xT 64K swizzled (phase-B B-frags, built
// once) + coefT 16K (xcpart overlay) + wn 2K + xc 4K + se 1K = 154.6 KB,
// 1 block/CU, grid 256 = one full-chip round.

#define CB 32
#define CI 512
#define CL 64
#define CO 128
#define OPB 16
#define NT 1024

typedef _Float16 half8 __attribute__((ext_vector_type(8)));
typedef float f32x4 __attribute__((ext_vector_type(4)));

static __device__ __forceinline__ _Float16 half_sel(uint v, int sh) {
  union { unsigned short s; _Float16 h; } c;
  c.s = (unsigned short)(v >> sh);
  return c.h;
}

// Gq layout (16B units): unit u = (o*8 + k)*64 + l1 holds pairs p=4k+q for
// ROW l1 (symmetric: == column l1): (G[o][l1][8k+2q], G[o][l1][8k+2q+1]),
// q = 0..3. Consecutive l1 -> consecutive 16B units => coalesced loads.
__global__ __launch_bounds__(256) void caps_gram(const float* __restrict__ wg,
                                                 __half2* __restrict__ Gq) {
  const int o = blockIdx.x;
  const int h = blockIdx.y;        // l1-half: rows h*32 .. h*32+31
  const int t = threadIdx.x;
  __shared__ float wl[64 * 65];    // W[o] padded (+1 col)
#pragma unroll
  for (int k = 0; k < 16; ++k) {
    int f = t + 256 * k;
    int j = f >> 6, l = f & 63;
    wl[j * 65 + l] = wg[(o << 12) + f];
  }
  __syncthreads();
  const int l1 = h * 32 + (t >> 3);
  const int kq = t & 7;            // l2 granule: l2 = 8*kq .. 8*kq+7
  const int l2b = kq << 3;
  float acc[8];
#pragma unroll
  for (int m = 0; m < 8; ++m) acc[m] = 0.f;
#pragma unroll 4
  for (int j = 0; j < 64; ++j) {
    float wa = wl[j * 65 + l1];
#pragma unroll
    for (int m = 0; m < 8; ++m) acc[m] += wa * wl[j * 65 + l2b + m];
  }
  union { __half2 h2[4]; uint4 u; } pk;
#pragma unroll
  for (int q = 0; q < 4; ++q)
    pk.h2[q] = __floats2half2_rn(acc[2 * q], acc[2 * q + 1]);
  reinterpret_cast<uint4*>(Gq)[(o << 9) + (kq << 6) + l1] = pk.u;
}

__global__ __launch_bounds__(NT, 4) void caps_main(const float* __restrict__ xg,
                                                   const float* __restrict__ wg,
                                                   const __half2* __restrict__ Gq,
                                                   float* __restrict__ outg) {
  const int b = blockIdx.y;
  const int obase = blockIdx.x * OPB;
  const int t = threadIdx.x;
  const int w = t >> 6;          // wave 0..15, owns capsule o = obase + w
  const int lane = t & 63;
  const int g = lane >> 4;
  const int o15 = lane & 15;

  __shared__ __align__(16) _Float16 xs[CI * CL];       // 65536 B
  __shared__ __align__(16) _Float16 xT[CL * CI];       // 65536 B (swizzled)
  __shared__ __align__(16) _Float16 coefT[OPB * CI];   // 16384 B (+xcpart ovl)
  __shared__ __align__(16) _Float16 wn16[OPB * CL];    // 2048 B (swizzled)
  __shared__ __align__(16) float xc_s[OPB * CL];       // 4096 B
  __shared__ float se_part[OPB * OPB];                 // 1024 B (pass 3 only)
  float* const xcpart = reinterpret_cast<float*>(coefT);  // [4][16][64] view
  char* const xs_b = reinterpret_cast<char*>(xs);
  char* const xT_b = reinterpret_cast<char*>(xT);
  char* const cf_b = reinterpret_cast<char*>(coefT);
  char* const wn_b = reinterpret_cast<char*>(wn16);
  // total 154624 B -> 1 block/CU, grid 256 = one full-chip round

  const int qh = w >> 2, nt = w & 3;  // phase-B: i-quarter, l-subtile
  const int lcol = nt * 16 + o15;     // this lane's xT row (l index)

  // G row pointer (16B units, coalesced: consecutive lanes adjacent)
  const uint4* Gp = reinterpret_cast<const uint4*>(Gq) +
                    ((obase + w) << 9) + lane;
  uint4 ga0, ga1, ga2, ga3;  // batch1 (k=0..3), <=16 extra live VGPRs

  // ---- stage x[b] -> fp16 subtiled LDS; coalesced float4 global reads ----
  {
    const float4* xg4 = reinterpret_cast<const float4*>(xg + b * (CI * CL));
#pragma unroll
    for (int k = 0; k < 4; ++k) {
      int f = t + NT * k;        // 8-half unit id: row i, l-unit lu
      int i = f >> 3, lu = f & 7;
      float4 a = xg4[2 * f];
      float4 c = xg4[2 * f + 1];
      union { _Float16 h[8]; uint4 u; } cv;
      cv.h[0] = (_Float16)a.x; cv.h[1] = (_Float16)a.y;
      cv.h[2] = (_Float16)a.z; cv.h[3] = (_Float16)a.w;
      cv.h[4] = (_Float16)c.x; cv.h[5] = (_Float16)c.y;
      cv.h[6] = (_Float16)c.z; cv.h[7] = (_Float16)c.w;
      int off = ((i >> 4) * 4 + (lu >> 1)) * 512 + (i & 15) * 32 + (lu & 1) * 16;
      *reinterpret_cast<uint4*>(xs_b + off) = cv.u;
    }
  }
  __syncthreads();

  // ---- build xT ONCE (paired-dword gather) + xbar partials (pass 0 B) ----
  {
    const uint* xrd32 = reinterpret_cast<const uint*>(
                            xs_b + nt * 512 + ((o15 & 8) << 1)) +
                        ((o15 & 7) >> 1);
    const int sh = (o15 & 1) << 4;
    float xbs = 0.f;
#define GATHW(K)                                                            \
  {                                                                         \
    int P = qh * 16 + (K)*4 + g;                                            \
    const uint* xk = xrd32 + (P >> 1) * 512 + (P & 1) * 64;                 \
    uint d0 = xk[0], d1 = xk[8], d2 = xk[16], d3 = xk[24];                  \
    uint d4 = xk[32], d5 = xk[40], d6 = xk[48], d7 = xk[56];                \
    union { _Float16 h[8]; uint4 u; } fv;                                   \
    fv.h[0] = half_sel(d0, sh); fv.h[1] = half_sel(d1, sh);                 \
    fv.h[2] = half_sel(d2, sh); fv.h[3] = half_sel(d3, sh);                 \
    fv.h[4] = half_sel(d4, sh); fv.h[5] = half_sel(d5, sh);                 \
    fv.h[6] = half_sel(d6, sh); fv.h[7] = half_sel(d7, sh);                 \
    xbs += (float)fv.h[0] + (float)fv.h[1] + (float)fv.h[2] +               \
           (float)fv.h[3] + (float)fv.h[4] + (float)fv.h[5] +               \
           (float)fv.h[6] + (float)fv.h[7];                                 \
    *reinterpret_cast<uint4*>(xT_b + lcol * 1024 +                          \
                              ((P ^ (lcol & 7)) << 4)) = fv.u;              \
  }
    GATHW(0) GATHW(1) GATHW(2) GATHW(3)
#undef GATHW
    xbs += __shfl_xor(xbs, 16, 64);
    xbs += __shfl_xor(xbs, 32, 64);
    if (lane < 16) xcpart[qh * 1024 + nt * 16 + lane] = xbs;  // [4][64] view
    ga0 = Gp[0]; ga1 = Gp[64]; ga2 = Gp[128]; ga3 = Gp[192];  // pass0 batch1
  }
  __syncthreads();

  for (int pass = 0; pass < 4; ++pass) {
    if (pass > 0) {
      // ---- phase A: logits for 16 o's via MFMA; exp -> coefT ----
      half8 bw0 = *reinterpret_cast<const half8*>(
          wn_b + o15 * 128 + ((g ^ (o15 & 7)) << 4));
      half8 bw1 = *reinterpret_cast<const half8*>(
          wn_b + o15 * 128 + (((4 + g) ^ (o15 & 7)) << 4));
      float sacc = 0.f;
#pragma unroll
      for (int ti = 0; ti < 2; ++ti) {
        const int st = 2 * w + ti;            // i-subtile, rows st*16..+15
        const int itb = st * 2048;
        half8 a0 = *reinterpret_cast<const half8*>(
            xs_b + itb + ((g >> 1) * 512) + o15 * 32 + ((g & 1) << 4));
        half8 a1 = *reinterpret_cast<const half8*>(
            xs_b + itb + ((2 + (g >> 1)) * 512) + o15 * 32 + ((g & 1) << 4));
        f32x4 d = {0.f, 0.f, 0.f, 0.f};
        d = __builtin_amdgcn_mfma_f32_16x16x32_f16(a0, bw0, d, 0, 0, 0);
        d = __builtin_amdgcn_mfma_f32_16x16x32_f16(a1, bw1, d, 0, 0, 0);
        // |logits| <= ||x_i||*sigma_max(W) ~ 2.5: softmax w/o max-sub is safe
        float e0 = __expf(d[0]), e1 = __expf(d[1]);
        float e2 = __expf(d[2]), e3 = __expf(d[3]);
        sacc += (e0 + e1) + (e2 + e3);
        int p = st * 2 + (g >> 1);
        union { _Float16 h[4]; uint2 u; } pk;
        pk.h[0] = (_Float16)e0; pk.h[1] = (_Float16)e1;
        pk.h[2] = (_Float16)e2; pk.h[3] = (_Float16)e3;
        *reinterpret_cast<uint2*>(cf_b + o15 * 1024 + ((p ^ o15) << 4) +
                                  ((g & 1) << 3)) = pk.u;
      }
      if (pass == 3) {  // softmax denominator needed only on the final pass
        sacc += __shfl_xor(sacc, 16, 64);
        sacc += __shfl_xor(sacc, 32, 64);
        if (lane < 16) se_part[w * 16 + lane] = sacc;  // [i-wave][o]
      }
      __syncthreads();

      // ---- phase B: xc partials, full 16-row MFMA, all b128 ----
      if (pass < 3) {  // batch1 G loads in flight under the MFMAs
        ga0 = Gp[0]; ga1 = Gp[64]; ga2 = Gp[128]; ga3 = Gp[192];
      }
      f32x4 d = {0.f, 0.f, 0.f, 0.f};
#define MFMAK(K)                                                            \
  {                                                                         \
    int p = qh * 16 + (K)*4 + g;                                            \
    half8 a = *reinterpret_cast<const half8*>(cf_b + o15 * 1024 +           \
                                              ((p ^ o15) << 4));            \
    half8 bv = *reinterpret_cast<const half8*>(xT_b + lcol * 1024 +         \
                                               ((p ^ (lcol & 7)) << 4));    \
    d = __builtin_amdgcn_mfma_f32_16x16x32_f16(a, bv, d, 0, 0, 0);          \
  }
      MFMAK(0) MFMAK(1) MFMAK(2) MFMAK(3)
#undef MFMAK
      __syncthreads();  // all coefT reads done before overlay write
#pragma unroll
      for (int r = 0; r < 4; ++r)
        xcpart[qh * 1024 + (g * 4 + r) * 64 + lcol] = d[r];  // [q][o][l]
    }
    __syncthreads();

    // ---- finalize: xc (unnormalized except pass 3); wn = G xc/||W xc|| ----
    {
      float sxc;
      if (pass == 0) {
        sxc = xcpart[lane] + xcpart[1024 + lane] + xcpart[2048 + lane] +
              xcpart[3072 + lane];
      } else {
        sxc = xcpart[w * 64 + lane] + xcpart[1024 + w * 64 + lane] +
              xcpart[2048 + w * 64 + lane] + xcpart[3072 + w * 64 + lane];
      }
      float xcv;
      if (pass == 3) {  // apply softmax denominator once, at the end
        float sp = se_part[(lane & 15) * 16 + w];
        sp += __shfl_xor(sp, 1, 64);
        sp += __shfl_xor(sp, 2, 64);
        sp += __shfl_xor(sp, 4, 64);
        sp += __shfl_xor(sp, 8, 64);
        xcv = sxc / sp;
      } else {
        xcv = sxc;  // scale cancels inside wn
      }
      xc_s[(w << 6) + lane] = xcv;
      if (pass < 3) {
        uint4 gb0 = Gp[256], gb1 = Gp[320], gb2 = Gp[384], gb3 = Gp[448];
        const float4* xc4 = reinterpret_cast<const float4*>(&xc_s[w << 6]);
        float u0 = 0.f, u1 = 0.f, u2 = 0.f, u3 = 0.f;
#define GDOT(V, K)                                                          \
  {                                                                         \
    float4 xa = xc4[2 * (K)], xb = xc4[2 * (K) + 1];                        \
    float2 h0 = __half22float2(*reinterpret_cast<const __half2*>(&V.x));    \
    float2 h1 = __half22float2(*reinterpret_cast<const __half2*>(&V.y));    \
    float2 h2 = __half22float2(*reinterpret_cast<const __half2*>(&V.z));    \
    float2 h3 = __half22float2(*reinterpret_cast<const __half2*>(&V.w));    \
    u0 += h0.x * xa.x; u1 += h0.y * xa.y;                                   \
    u2 += h1.x * xa.z; u3 += h1.y * xa.w;                                   \
    u0 += h2.x * xb.x; u1 += h2.y * xb.y;                                   \
    u2 += h3.x * xb.z; u3 += h3.y * xb.w;                                   \
  }
        GDOT(ga0, 0) GDOT(ga1, 1) GDOT(ga2, 2) GDOT(ga3, 3)
        GDOT(gb0, 4) GDOT(gb1, 5) GDOT(gb2, 6) GDOT(gb3, 7)
#undef GDOT
        float uv = (u0 + u1) + (u2 + u3);
        float sq = uv * xcv;
#pragma unroll
        for (int m = 32; m; m >>= 1) sq += __shfl_xor(sq, m, 64);
        float wnv = uv / fmaxf(sqrtf(fmaxf(sq, 0.f)), 1e-12f);
        union { _Float16 hf; unsigned short us; } wc;
        wc.hf = (_Float16)wnv;
        *reinterpret_cast<unsigned short*>(
            wn_b + w * 128 + (((lane >> 3) ^ (w & 7)) << 4) +
            ((lane & 7) << 1)) = wc.us;
      }
    }
    __syncthreads();
  }

  // ---- epilogue: out[b, obase+w, j=lane] = sum_l W[o][j][l] * xc[o][l] ----
  {
    const float* Wp = wg + ((((obase + w) << 6) + lane) << 6);
    float a0 = 0.f, a1 = 0.f, a2 = 0.f, a3 = 0.f;
#pragma unroll
    for (int k = 0; k < 16; ++k) {
      float4 wv = *reinterpret_cast<const float4*>(&Wp[k << 2]);
      float4 xv = *reinterpret_cast<const float4*>(&xc_s[(w << 6) + (k << 2)]);
      a0 += wv.x * xv.x; a1 += wv.y * xv.y;
      a2 += wv.z * xv.z; a3 += wv.w * xv.w;
    }
    outg[((b << 7) + obase + w) * 64 + lane] = (a0 + a1) + (a2 + a3);
  }
}

extern "C" void kernel_launch(void* const* d_in, const int* in_sizes, int n_in,
                              void* d_out, int out_size, void* d_ws, size_t ws_size,
                              hipStream_t stream) {
  const float* x = (const float*)d_in[0];     // (32, 512, 64) fp32
  const float* wgt = (const float*)d_in[1];   // (128, 64, 64) fp32
  float* out = (float*)d_out;                 // (32, 128, 64) fp32
  __half2* Gq = (__half2*)d_ws;               // 128*8*64 x 16B = 1 MB

  caps_gram<<<dim3(CO, 2), dim3(256), 0, stream>>>(wgt, Gq);
  caps_main<<<dim3(CO / OPB, CB), dim3(NT), 0, stream>>>(x, wgt, Gq, out);
}

// Round 14
// 33.054 us; speedup vs baseline: 2.1058x; 1.0642x over previous
//
#include <hip/hip_runtime.h>
#include <hip/hip_fp16.h>

// CapsuleLinear, B=32, I=512, L=64, O=128, J=64, 3 routing iterations.
// Algebraic fusion (no priors): out = W_o @ xc, wn = (G_o @ xc)/||W_o xc||,
// G_o = W_o^T W_o (fp16 lane-major Gq, 1 MB in d_ws).
// r14 vs r13 (each trims serialization, none touches verified indexing):
//  - phase-A A-frags hoisted into 4 named half8 (16 persistent VGPRs): same
//    two i-subtiles per wave every pass -> load once; xs dead after setup
//  - xcpart lives in the dead xs region (not over coefT): the mid-phase-B
//    overlay barrier is gone -> 3 barriers/pass
//  - G dots double-buffered in 2-uint4 rounds: <=16 G regs, latency hidden
// Scale invariance (r13): softmax denominator applied only on the last pass.
// LDS: xs 64K (setup; first 16K becomes xcpart) + xT 64K + coefT 16K + wn 2K
// + xc 4K + se 1K = 154.6 KB, 1 block/CU, grid 256 = one full-chip round.

#define CB 32
#define CI 512
#define CL 64
#define CO 128
#define OPB 16
#define NT 1024

typedef _Float16 half8 __attribute__((ext_vector_type(8)));
typedef float f32x4 __attribute__((ext_vector_type(4)));

static __device__ __forceinline__ _Float16 half_sel(uint v, int sh) {
  union { unsigned short s; _Float16 h; } c;
  c.s = (unsigned short)(v >> sh);
  return c.h;
}

// Gq layout (16B units): unit u = (o*8 + k)*64 + l1 holds pairs p=4k+q for
// ROW l1 (symmetric == column l1): (G[o][l1][8k+2q], G[o][l1][8k+2q+1]).
__global__ __launch_bounds__(256) void caps_gram(const float* __restrict__ wg,
                                                 __half2* __restrict__ Gq) {
  const int o = blockIdx.x;
  const int h = blockIdx.y;        // l1-half: rows h*32 .. h*32+31
  const int t = threadIdx.x;
  __shared__ float wl[64 * 65];    // W[o] padded (+1 col)
#pragma unroll
  for (int k = 0; k < 16; ++k) {
    int f = t + 256 * k;
    int j = f >> 6, l = f & 63;
    wl[j * 65 + l] = wg[(o << 12) + f];
  }
  __syncthreads();
  const int l1 = h * 32 + (t >> 3);
  const int kq = t & 7;
  const int l2b = kq << 3;
  float acc[8];
#pragma unroll
  for (int m = 0; m < 8; ++m) acc[m] = 0.f;
#pragma unroll 4
  for (int j = 0; j < 64; ++j) {
    float wa = wl[j * 65 + l1];
#pragma unroll
    for (int m = 0; m < 8; ++m) acc[m] += wa * wl[j * 65 + l2b + m];
  }
  union { __half2 h2[4]; uint4 u; } pk;
#pragma unroll
  for (int q = 0; q < 4; ++q)
    pk.h2[q] = __floats2half2_rn(acc[2 * q], acc[2 * q + 1]);
  reinterpret_cast<uint4*>(Gq)[(o << 9) + (kq << 6) + l1] = pk.u;
}

__global__ __launch_bounds__(NT, 4) void caps_main(const float* __restrict__ xg,
                                                   const float* __restrict__ wg,
                                                   const __half2* __restrict__ Gq,
                                                   float* __restrict__ outg) {
  const int b = blockIdx.y;
  const int obase = blockIdx.x * OPB;
  const int t = threadIdx.x;
  const int w = t >> 6;          // wave 0..15, owns capsule o = obase + w
  const int lane = t & 63;
  const int g = lane >> 4;
  const int o15 = lane & 15;

  __shared__ __align__(16) _Float16 xs[CI * CL];       // 65536 B (setup only)
  __shared__ __align__(16) _Float16 xT[CL * CI];       // 65536 B (swizzled)
  __shared__ __align__(16) _Float16 coefT[OPB * CI];   // 16384 B (dedicated)
  __shared__ __align__(16) _Float16 wn16[OPB * CL];    // 2048 B (swizzled)
  __shared__ __align__(16) float xc_s[OPB * CL];       // 4096 B
  __shared__ float se_part[OPB * OPB];                 // 1024 B (pass 3 only)
  float* const xcpart = reinterpret_cast<float*>(xs);  // 16 KB in dead xs
  char* const xs_b = reinterpret_cast<char*>(xs);
  char* const xT_b = reinterpret_cast<char*>(xT);
  char* const cf_b = reinterpret_cast<char*>(coefT);
  char* const wn_b = reinterpret_cast<char*>(wn16);
  // total 154624 B -> 1 block/CU, grid 256 = one full-chip round

  const int qh = w >> 2, nt = w & 3;  // phase-B: i-quarter, l-subtile
  const int lcol = nt * 16 + o15;     // this lane's xT row (l index)

  // G row pointer (16B units, coalesced across lanes)
  const uint4* Gp = reinterpret_cast<const uint4*>(Gq) +
                    ((obase + w) << 9) + lane;
  uint4 ga0, ga1;  // G double-buffer half (<=8 regs across barriers)

  // ---- stage x[b] -> fp16 subtiled LDS; coalesced float4 global reads ----
  {
    const float4* xg4 = reinterpret_cast<const float4*>(xg + b * (CI * CL));
#pragma unroll
    for (int k = 0; k < 4; ++k) {
      int f = t + NT * k;        // 8-half unit id: row i, l-unit lu
      int i = f >> 3, lu = f & 7;
      float4 a = xg4[2 * f];
      float4 c = xg4[2 * f + 1];
      union { _Float16 h[8]; uint4 u; } cv;
      cv.h[0] = (_Float16)a.x; cv.h[1] = (_Float16)a.y;
      cv.h[2] = (_Float16)a.z; cv.h[3] = (_Float16)a.w;
      cv.h[4] = (_Float16)c.x; cv.h[5] = (_Float16)c.y;
      cv.h[6] = (_Float16)c.z; cv.h[7] = (_Float16)c.w;
      int off = ((i >> 4) * 4 + (lu >> 1)) * 512 + (i & 15) * 32 + (lu & 1) * 16;
      *reinterpret_cast<uint4*>(xs_b + off) = cv.u;
    }
  }
  __syncthreads();

  // ---- setup: build xT once; hoist A-frags; xbar partials; G preload ----
  float xbs = 0.f;
  half8 af00, af01, af10, af11;  // phase-A A-frags, pass-invariant (16 VGPRs)
  {
    const uint* xrd32 = reinterpret_cast<const uint*>(
                            xs_b + nt * 512 + ((o15 & 8) << 1)) +
                        ((o15 & 7) >> 1);
    const int sh = (o15 & 1) << 4;
#define GATHW(K)                                                            \
  {                                                                         \
    int P = qh * 16 + (K)*4 + g;                                            \
    const uint* xk = xrd32 + (P >> 1) * 512 + (P & 1) * 64;                 \
    uint d0 = xk[0], d1 = xk[8], d2 = xk[16], d3 = xk[24];                  \
    uint d4 = xk[32], d5 = xk[40], d6 = xk[48], d7 = xk[56];                \
    union { _Float16 h[8]; uint4 u; } fv;                                   \
    fv.h[0] = half_sel(d0, sh); fv.h[1] = half_sel(d1, sh);                 \
    fv.h[2] = half_sel(d2, sh); fv.h[3] = half_sel(d3, sh);                 \
    fv.h[4] = half_sel(d4, sh); fv.h[5] = half_sel(d5, sh);                 \
    fv.h[6] = half_sel(d6, sh); fv.h[7] = half_sel(d7, sh);                 \
    xbs += (float)fv.h[0] + (float)fv.h[1] + (float)fv.h[2] +               \
           (float)fv.h[3] + (float)fv.h[4] + (float)fv.h[5] +               \
           (float)fv.h[6] + (float)fv.h[7];                                 \
    *reinterpret_cast<uint4*>(xT_b + lcol * 1024 +                          \
                              ((P ^ (lcol & 7)) << 4)) = fv.u;              \
  }
    GATHW(0) GATHW(1) GATHW(2) GATHW(3)
#undef GATHW
    // A-frags: wave w's i-subtiles st = 2w, 2w+1 (same addresses every pass)
    const int abase = (g >> 1) * 512 + o15 * 32 + ((g & 1) << 4);
    af00 = *reinterpret_cast<const half8*>(xs_b + (2 * w) * 2048 + abase);
    af01 = *reinterpret_cast<const half8*>(xs_b + (2 * w) * 2048 + 1024 + abase);
    af10 = *reinterpret_cast<const half8*>(xs_b + (2 * w + 1) * 2048 + abase);
    af11 = *reinterpret_cast<const half8*>(xs_b + (2 * w + 1) * 2048 + 1024 + abase);
    xbs += __shfl_xor(xbs, 16, 64);
    xbs += __shfl_xor(xbs, 32, 64);
    ga0 = Gp[0]; ga1 = Gp[64];  // pass-0 G first pair
  }
  __syncthreads();  // ALL xs reads complete before xcpart overlays it
  if (lane < 16) xcpart[qh * 1024 + nt * 16 + lane] = xbs;  // xbar partials

  for (int pass = 0; pass < 4; ++pass) {
    if (pass > 0) {
      // ---- phase A: logits via MFMA (A-frags from regs); exp -> coefT ----
      half8 bw0 = *reinterpret_cast<const half8*>(
          wn_b + o15 * 128 + ((g ^ (o15 & 7)) << 4));
      half8 bw1 = *reinterpret_cast<const half8*>(
          wn_b + o15 * 128 + (((4 + g) ^ (o15 & 7)) << 4));
      float sacc = 0.f;
#define PHASEA(TI, AF0, AF1)                                                \
  {                                                                         \
    const int st = 2 * w + (TI);                                            \
    f32x4 d = {0.f, 0.f, 0.f, 0.f};                                         \
    d = __builtin_amdgcn_mfma_f32_16x16x32_f16(AF0, bw0, d, 0, 0, 0);       \
    d = __builtin_amdgcn_mfma_f32_16x16x32_f16(AF1, bw1, d, 0, 0, 0);       \
    float e0 = __expf(d[0]), e1 = __expf(d[1]);                             \
    float e2 = __expf(d[2]), e3 = __expf(d[3]);                             \
    sacc += (e0 + e1) + (e2 + e3);                                          \
    int p = st * 2 + (g >> 1);                                              \
    union { _Float16 h[4]; uint2 u; } pk;                                   \
    pk.h[0] = (_Float16)e0; pk.h[1] = (_Float16)e1;                         \
    pk.h[2] = (_Float16)e2; pk.h[3] = (_Float16)e3;                         \
    *reinterpret_cast<uint2*>(cf_b + o15 * 1024 + ((p ^ o15) << 4) +        \
                              ((g & 1) << 3)) = pk.u;                       \
  }
      PHASEA(0, af00, af01)
      PHASEA(1, af10, af11)
#undef PHASEA
      if (pass == 3) {  // softmax denominator only needed on the final pass
        sacc += __shfl_xor(sacc, 16, 64);
        sacc += __shfl_xor(sacc, 32, 64);
        if (lane < 16) se_part[w * 16 + lane] = sacc;  // [i-wave][o]
      }
      __syncthreads();

      // ---- phase B: xc partials, full 16-row MFMA, b128 reads ----
      f32x4 d = {0.f, 0.f, 0.f, 0.f};
#define MFMAK(K)                                                            \
  {                                                                         \
    int p = qh * 16 + (K)*4 + g;                                            \
    half8 a = *reinterpret_cast<const half8*>(cf_b + o15 * 1024 +           \
                                              ((p ^ o15) << 4));            \
    half8 bv = *reinterpret_cast<const half8*>(xT_b + lcol * 1024 +         \
                                               ((p ^ (lcol & 7)) << 4));    \
    d = __builtin_amdgcn_mfma_f32_16x16x32_f16(a, bv, d, 0, 0, 0);          \
  }
      MFMAK(0) MFMAK(1) MFMAK(2) MFMAK(3)
#undef MFMAK
      if (pass < 3) { ga0 = Gp[0]; ga1 = Gp[64]; }  // G pair in flight
#pragma unroll
      for (int r = 0; r < 4; ++r)  // dedicated xcpart: no barrier needed
        xcpart[qh * 1024 + (g * 4 + r) * 64 + lcol] = d[r];
    }
    __syncthreads();

    // ---- finalize: xc (unnormalized until pass 3); wn = G xc/||W xc|| ----
    {
      float sxc;
      if (pass == 0) {
        sxc = xcpart[lane] + xcpart[1024 + lane] + xcpart[2048 + lane] +
              xcpart[3072 + lane];
      } else {
        sxc = xcpart[w * 64 + lane] + xcpart[1024 + w * 64 + lane] +
              xcpart[2048 + w * 64 + lane] + xcpart[3072 + w * 64 + lane];
      }
      float xcv;
      if (pass == 3) {  // apply softmax denominator once at the end
        float sp = se_part[(lane & 15) * 16 + w];
        sp += __shfl_xor(sp, 1, 64);
        sp += __shfl_xor(sp, 2, 64);
        sp += __shfl_xor(sp, 4, 64);
        sp += __shfl_xor(sp, 8, 64);
        xcv = sxc / sp;
      } else {
        xcv = sxc;  // scale cancels inside wn
      }
      xc_s[(w << 6) + lane] = xcv;
      if (pass < 3) {
        const float4* xc4 = reinterpret_cast<const float4*>(&xc_s[w << 6]);
        float u0 = 0.f, u1 = 0.f, u2 = 0.f, u3 = 0.f;
#define GDOT(V, K)                                                          \
  {                                                                         \
    float4 xa = xc4[2 * (K)], xb = xc4[2 * (K) + 1];                        \
    float2 h0 = __half22float2(*reinterpret_cast<const __half2*>(&V.x));    \
    float2 h1 = __half22float2(*reinterpret_cast<const __half2*>(&V.y));    \
    float2 h2 = __half22float2(*reinterpret_cast<const __half2*>(&V.z));    \
    float2 h3 = __half22float2(*reinterpret_cast<const __half2*>(&V.w));    \
    u0 += h0.x * xa.x; u1 += h0.y * xa.y;                                   \
    u2 += h1.x * xa.z; u3 += h1.y * xa.w;                                   \
    u0 += h2.x * xb.x; u1 += h2.y * xb.y;                                   \
    u2 += h3.x * xb.z; u3 += h3.y * xb.w;                                   \
  }
        // double-buffered G: <=16 G regs live, each load hidden under GDOTs
        uint4 gb0 = Gp[128], gb1 = Gp[192];
        GDOT(ga0, 0) GDOT(ga1, 1)
        ga0 = Gp[256]; ga1 = Gp[320];
        GDOT(gb0, 2) GDOT(gb1, 3)
        gb0 = Gp[384]; gb1 = Gp[448];
        GDOT(ga0, 4) GDOT(ga1, 5)
        GDOT(gb0, 6) GDOT(gb1, 7)
#undef GDOT
        float uv = (u0 + u1) + (u2 + u3);
        float sq = uv * xcv;
#pragma unroll
        for (int m = 32; m; m >>= 1) sq += __shfl_xor(sq, m, 64);
        float wnv = uv / fmaxf(sqrtf(fmaxf(sq, 0.f)), 1e-12f);
        union { _Float16 hf; unsigned short us; } wc;
        wc.hf = (_Float16)wnv;
        *reinterpret_cast<unsigned short*>(
            wn_b + w * 128 + (((lane >> 3) ^ (w & 7)) << 4) +
            ((lane & 7) << 1)) = wc.us;
      }
    }
    __syncthreads();
  }

  // ---- epilogue: out[b, obase+w, j=lane] = sum_l W[o][j][l] * xc[o][l] ----
  {
    const float* Wp = wg + ((((obase + w) << 6) + lane) << 6);
    float a0 = 0.f, a1 = 0.f, a2 = 0.f, a3 = 0.f;
#pragma unroll
    for (int k = 0; k < 16; ++k) {
      float4 wv = *reinterpret_cast<const float4*>(&Wp[k << 2]);
      float4 xv = *reinterpret_cast<const float4*>(&xc_s[(w << 6) + (k << 2)]);
      a0 += wv.x * xv.x; a1 += wv.y * xv.y;
      a2 += wv.z * xv.z; a3 += wv.w * xv.w;
    }
    outg[((b << 7) + obase + w) * 64 + lane] = (a0 + a1) + (a2 + a3);
  }
}

extern "C" void kernel_launch(void* const* d_in, const int* in_sizes, int n_in,
                              void* d_out, int out_size, void* d_ws, size_t ws_size,
                              hipStream_t stream) {
  const float* x = (const float*)d_in[0];     // (32, 512, 64) fp32
  const float* wgt = (const float*)d_in[1];   // (128, 64, 64) fp32
  float* out = (float*)d_out;                 // (32, 128, 64) fp32
  __half2* Gq = (__half2*)d_ws;               // 128*8*64 x 16B = 1 MB

  caps_gram<<<dim3(CO, 2), dim3(256), 0, stream>>>(wgt, Gq);
  caps_main<<<dim3(CO / OPB, CB), dim3(NT), 0, stream>>>(x, wgt, Gq, out);
}